// Round 5
// baseline (136.469 us; speedup 1.0000x reference)
//
#include <hip/hip_runtime.h>
#include <cstdint>

#define IMG_H 512
#define IMG_W 512
#define ROW_BYTES (IMG_W * 4)
#define NPLANES 48                  // 16 batch * 3 channels
#define PLANE_SZ (IMG_H * IMG_W)
#define N_ELEM (NPLANES * PLANE_SZ) // 12,582,912

#define TILE_W 48
#define TILE_H 32
#define GX 11
#define GY 16
#define NBLOCKS (GX * GY * NPLANES) // 8448
#define NPART (NBLOCKS * 4)         // one fp32 partial per wave: 33792
#define VPITCH 59                   // stored halo cols 0..57 (+1 pad)

#define SSIM_C1 1e-4f
#define SSIM_C2 9e-4f

typedef float v2f __attribute__((ext_vector_type(2)));

// Raw buffer load: OOB (row<0 / row>=H via soffset; bad col via huge voffset)
// returns 0.0f in hardware = free 'SAME' zero padding, zero bounds VALU.
typedef int rsrc_t __attribute__((ext_vector_type(4)));
__device__ float
llvm_amdgcn_raw_buffer_load_fp32(rsrc_t srsrc, int voffset, int soffset,
                                 int glc_slc) __asm("llvm.amdgcn.raw.buffer.load.f32");

__device__ inline rsrc_t make_rsrc(const void* p, int bytes) {
    rsrc_t r;
    r.x = (int)(uint32_t)(uintptr_t)p;       // base lo
    r.y = (int)((uintptr_t)p >> 32);         // base hi, stride=0
    r.z = bytes;                             // num_records (bytes)
    r.w = 0x00020000;                        // raw dword SRD word3
    return r;
}

// Separable 11x11 Gaussian over packed channel pairs P=(s,d), Q=(s2,d2)
// [s=x+y, d=x-y] via v_pk_fma_f32. BARRIER-FREE: each wave's horizontal pass
// reads only the 8 LDS rows that wave wrote (intra-wave lgkmcnt ordering),
// and each wave stores its own fp32 partial. No __syncthreads anywhere.
__global__ __launch_bounds__(256, 5) void ssim_tile_kernel(
    const float* __restrict__ img1, const float* __restrict__ img2,
    float* __restrict__ partials)
{
    __shared__ float4 vs[TILE_H][VPITCH]; // 30.2 KB -> 5 blocks/CU (20 waves)

    // exact gaussian(ws=11, sigma=1.5) weights (normalized, ~1e-8 abs)
    const float gw[11] = {0.00102838f, 0.00759876f, 0.03600077f, 0.10936069f,
                          0.21300553f, 0.26601172f, 0.21300553f, 0.10936069f,
                          0.03600077f, 0.00759876f, 0.00102838f};

    const int tid  = threadIdx.x;
    const int lane = tid & 63;
    const int wv   = tid >> 6;
    const int r0   = wv * 8;                 // this wave's 8 output rows
    const int ox = blockIdx.x * TILE_W;
    const int oy = blockIdx.y * TILE_H;

    const float* p1 = img1 + (size_t)blockIdx.z * PLANE_SZ;
    const float* p2 = img2 + (size_t)blockIdx.z * PLANE_SZ;
    const rsrc_t rr1 = make_rsrc(p1, PLANE_SZ * 4);
    const rsrc_t rr2 = make_rsrc(p2, PLANE_SZ * 4);

    // ---- vertical pass: lane = halo col, rows oy+r0-5 .. oy+r0+12
    {
        const int srow0 = __builtin_amdgcn_readfirstlane(oy + r0 - 5); // SGPR
        const int gcol = ox + lane - 5;
        const int coff = ((unsigned)gcol < (unsigned)IMG_W) ? (gcol * 4) : 0x48000000;

        float xs[18], ys[18];
        #pragma unroll
        for (int i = 0; i < 18; ++i) {
            const int soff = (srow0 + i) * ROW_BYTES;  // SGPR soffset
            xs[i] = llvm_amdgcn_raw_buffer_load_fp32(rr1, coff, soff, 0);
            ys[i] = llvm_amdgcn_raw_buffer_load_fp32(rr2, coff, soff, 0);
        }

        v2f accP[8], accQ[8];
        #pragma unroll
        for (int o = 0; o < 8; ++o) { accP[o] = (v2f)(0.f); accQ[o] = (v2f)(0.f); }
        #pragma unroll
        for (int i = 0; i < 18; ++i) {
            v2f P; P.x = xs[i] + ys[i]; P.y = xs[i] - ys[i];
            const v2f Q = P * P;                       // v_pk_mul_f32
            #pragma unroll
            for (int o = 0; o < 8; ++o) {
                const int k = i - o;                   // tap index (static)
                if (k >= 0 && k <= 10) {
                    const v2f w2 = (v2f)(gw[k]);
                    accP[o] = __builtin_elementwise_fma(P, w2, accP[o]); // v_pk_fma_f32
                    accQ[o] = __builtin_elementwise_fma(Q, w2, accQ[o]);
                }
            }
        }
        if (lane < 58) {                               // only cols horizontal reads
            #pragma unroll
            for (int o = 0; o < 8; ++o)
                vs[r0 + o][lane] = make_float4(accP[o].x, accP[o].y,
                                               accQ[o].x, accQ[o].y);
        }
    }
    // NO barrier: this wave reads back only rows r0..r0+7 it just wrote;
    // compiler-inserted s_waitcnt lgkmcnt orders intra-wave LDS write->read.

    // ---- horizontal pass + SSIM: lane -> row r0+(lane>>3), 6 consecutive cols
    float lsum = 0.f;
    {
        const int r  = r0 + (lane >> 3);
        const int c0 = (lane & 7) * 6;                 // max read col 42+15=57
        v2f mP[6], mQ[6];
        #pragma unroll
        for (int j = 0; j < 6; ++j) { mP[j] = (v2f)(0.f); mQ[j] = (v2f)(0.f); }
        #pragma unroll
        for (int t = 0; t < 16; ++t) {
            const float4 v = vs[r][c0 + t];
            v2f vP; vP.x = v.x; vP.y = v.y;
            v2f vQ; vQ.x = v.z; vQ.y = v.w;
            #pragma unroll
            for (int j = 0; j < 6; ++j) {
                const int k = t - j;
                if (k >= 0 && k <= 10) {
                    const v2f w2 = (v2f)(gw[k]);
                    mP[j] = __builtin_elementwise_fma(vP, w2, mP[j]);
                    mQ[j] = __builtin_elementwise_fma(vQ, w2, mQ[j]);
                }
            }
        }
        #pragma unroll
        for (int j = 0; j < 6; ++j) {
            if (ox + c0 + j < IMG_W) {                 // clip right-edge tile
                const float mus = mP[j].x, mud = mP[j].y;
                const float es2 = mQ[j].x, ed2 = mQ[j].y;
                const float a = mus * mus, b = mud * mud;
                // mu1 = (mus+mud)/2, mu2 = (mus-mud)/2:
                const float num1 = (a - b) * 0.5f + SSIM_C1;               // 2*mu1*mu2 + C1
                const float den1 = (a + b) * 0.5f + SSIM_C1;               // mu1^2+mu2^2 + C1
                const float num2 = (es2 - ed2 - (a - b)) * 0.5f + SSIM_C2; // 2*sigma12 + C2
                const float den2 = (es2 + ed2 - (a + b)) * 0.5f + SSIM_C2; // s1+s2 + C2
                lsum += (num1 * num2) * __builtin_amdgcn_rcpf(den1 * den2);
            }
        }
    }

    // ---- per-wave reduction -> fp32 partial, plain store, no cross-wave sync
    #pragma unroll
    for (int off = 32; off > 0; off >>= 1)
        lsum += __shfl_down(lsum, off, 64);
    if (lane == 0) {
        const int bid = blockIdx.x + GX * (blockIdx.y + GY * blockIdx.z);
        partials[(bid << 2) | wv] = lsum;
    }
}

// 1 block x 1024 threads: 33 independent fp32 loads/thread, f64 accumulate.
__global__ __launch_bounds__(1024) void ssim_finalize_kernel(
    const float* __restrict__ partials, float* __restrict__ out)
{
    __shared__ double wred[16];
    const int tid  = threadIdx.x;
    const int lane = tid & 63;
    const int wv   = tid >> 6;
    double s = 0.0;
    #pragma unroll
    for (int i = 0; i < 33; ++i)               // 33*1024 == 33792 exactly
        s += (double)partials[tid + i * 1024];
    #pragma unroll
    for (int off = 32; off > 0; off >>= 1)
        s += __shfl_down(s, off, 64);
    if (lane == 0) wred[wv] = s;
    __syncthreads();
    if (wv == 0) {
        double v = (lane < 16) ? wred[lane] : 0.0;
        v += __shfl_down(v, 8, 64);
        v += __shfl_down(v, 4, 64);
        v += __shfl_down(v, 2, 64);
        v += __shfl_down(v, 1, 64);
        if (lane == 0) out[0] = (float)(v / (double)N_ELEM);
    }
}

extern "C" void kernel_launch(void* const* d_in, const int* in_sizes, int n_in,
                              void* d_out, int out_size, void* d_ws, size_t ws_size,
                              hipStream_t stream)
{
    const float* img1 = (const float*)d_in[0];
    const float* img2 = (const float*)d_in[1];
    float* partials   = (float*)d_ws;           // 33792 * 4B = 135 KB scratch
    float* out        = (float*)d_out;

    dim3 grid(GX, GY, NPLANES);
    ssim_tile_kernel<<<grid, dim3(256), 0, stream>>>(img1, img2, partials);
    ssim_finalize_kernel<<<1, dim3(1024), 0, stream>>>(partials, out);
}